// Round 5
// baseline (2592.697 us; speedup 1.0000x reference)
//
#include <hip/hip_runtime.h>
#include <hip/hip_bf16.h>

// ---------------- problem constants ----------------
static constexpr int BATCH = 64;
static constexpr int SEQ   = 256;
static constexpr int ED    = 300;   // embed dim
static constexpr int HD    = 300;   // hidden dim
static constexpr int HPAD  = 320;   // hidden padded to mult of 32
static constexpr int GPAD  = 1280;  // 4*HPAD, quad-interleaved gate rows
static constexpr int NTAG  = 12;
static constexpr int NWG_DIR = 10;  // recurrent WGs per direction
static constexpr int NH      = 32;  // hidden units per recurrent WG

// ---------------- workspace layout (bytes) ----------------
static constexpr size_t O_GIN  = 0;                                     // bf16 [2][SEQ][BATCH][GPAD]
static constexpr size_t SZ_GIN = (size_t)2*SEQ*BATCH*GPAD*2;            // 83,886,080
static constexpr size_t O_H    = O_GIN + SZ_GIN;                        // bf16 [2][SEQ][NWG_DIR][BATCH][32]
static constexpr size_t SZ_H   = (size_t)2*SEQ*NWG_DIR*BATCH*NH*2;      // 20,971,520
static constexpr size_t O_WHH  = O_H + SZ_H;                            // bf16 [2][GPAD][HPAD]
static constexpr size_t SZ_WHH = (size_t)2*GPAD*HPAD*2;
static constexpr size_t O_WIH  = O_WHH + SZ_WHH;                        // bf16 [2][GPAD][HPAD]
static constexpr size_t SZ_WIH = (size_t)2*GPAD*HPAD*2;
static constexpr size_t O_BIAS = O_WIH + SZ_WIH;                        // f32 [2][GPAD]
static constexpr size_t SZ_BIAS= (size_t)2*GPAD*4;
static constexpr size_t O_EMIT = O_BIAS + SZ_BIAS;                      // f32 [SEQ][BATCH][NTAG]
static constexpr size_t SZ_EMIT= (size_t)SEQ*BATCH*NTAG*4;
static constexpr size_t O_CTR  = O_EMIT + SZ_EMIT;                      // int flags[2*NWG_DIR][16]

// ---------------- types / helpers ----------------
typedef __bf16 bf16x8 __attribute__((ext_vector_type(8)));
typedef float  f32x4  __attribute__((ext_vector_type(4)));
typedef unsigned short u16x8 __attribute__((ext_vector_type(8)));
typedef unsigned short u16;
typedef unsigned long long u64;

__device__ __forceinline__ float bu(u16 u){ union{unsigned i; float f;} x; x.i = ((unsigned)u)<<16; return x.f; }
__device__ __forceinline__ u16 fb(float f){ union{float f; unsigned i;} x; x.f = f; unsigned r = x.i + 0x7FFFu + ((x.i>>16)&1u); return (u16)(r>>16); }
__device__ __forceinline__ float sigf(float x){ return 1.0f/(1.0f + __expf(-x)); }
__device__ __forceinline__ float tanh_(float x){ return 2.0f*sigf(2.0f*x) - 1.0f; }
__device__ __forceinline__ f32x4 mfma16(bf16x8 a, bf16x8 b, f32x4 c){
  return __builtin_amdgcn_mfma_f32_16x16x32_bf16(a, b, c, 0, 0, 0);
}
__device__ __forceinline__ int swz4(int r){ return ((r + (r>>2)) & 3); }

// ============================================================
// K0: pack W_hh / W_ih into bf16, quad-interleaved rows (R = j*4+gate),
// zero-padded to [GPAD][HPAD]; pack bias; zero sync flags.
// ============================================================
__global__ __launch_bounds__(256) void k0_pack(
    const float* whf, const float* whb, const float* wif, const float* wib,
    const float* bfv, const float* bbv,
    u16* wpkhh, u16* wpkih, float* biasPk, int* flags)
{
  int idx = blockIdx.x*256 + threadIdx.x;                 // 0 .. 2*2*GPAD*HPAD-1
  int mat = idx / (2*GPAD*HPAD);                          // 0 = hh, 1 = ih
  int rem = idx % (2*GPAD*HPAD);
  int dd  = rem / (GPAD*HPAD);
  int rr  = rem % (GPAD*HPAD);
  int R   = rr / HPAD, kk = rr % HPAD;
  int jj  = R >> 2, gate = R & 3;
  float v = 0.f;
  if (jj < HD && kk < HD){
    const float* src = mat ? (dd ? wib : wif) : (dd ? whb : whf);
    v = src[(size_t)(gate*HD + jj)*ED + kk];              // ED == HD == 300
  }
  (mat ? wpkih : wpkhh)[rem] = fb(v);
  if (idx < 2*GPAD){
    int d2 = idx / GPAD, R2 = idx % GPAD;
    int j2 = R2 >> 2, g2 = R2 & 3;
    biasPk[idx] = (j2 < HD) ? (d2 ? bbv : bfv)[g2*HD + j2] : 0.f;
  }
  if (idx < 2*NWG_DIR*16) flags[idx] = 0;
}

// ============================================================
// K1: g_in = embed[sent] @ W_ih_packed^T + bias   (bf16 MFMA GEMM)
// ============================================================
__global__ __launch_bounds__(256) void k1_gin(
    const int* sent, const float* embed, const u16* wpkih,
    const float* biasPk, u16* gin)
{
  int blk = blockIdx.x;
  int mb = blk / 40, nb = blk % 40;     // mb == t
  int tid = threadIdx.x, lane = tid & 63, w = tid >> 6;

  __shared__ int srow[64];
  __shared__ u16 sA[64*32];
  __shared__ u16 sB[64*32];

  if (tid < 64) srow[tid] = sent[(size_t)tid*SEQ + mb];
  __syncthreads();

  f32x4 acc[4] = {f32x4{0,0,0,0},f32x4{0,0,0,0},f32x4{0,0,0,0},f32x4{0,0,0,0}};
  int r = tid >> 2, cc = tid & 3;
  int col = lane & 15, hi = lane >> 4;

  for (int k0 = 0; k0 < 10; k0++){
    {
      int kbase = k0*32 + cc*8;
      const float* erow = embed + (size_t)srow[r]*ED;
      float v[8];
      if (kbase + 8 <= ED){
        float4 p0 = *(const float4*)(erow + kbase);
        float4 p1 = *(const float4*)(erow + kbase + 4);
        v[0]=p0.x; v[1]=p0.y; v[2]=p0.z; v[3]=p0.w;
        v[4]=p1.x; v[5]=p1.y; v[6]=p1.z; v[7]=p1.w;
      } else {
        #pragma unroll
        for (int e = 0; e < 8; e++) v[e] = (kbase + e < ED) ? erow[kbase + e] : 0.f;
      }
      u16x8 pk;
      #pragma unroll
      for (int e = 0; e < 8; e++) pk[e] = fb(v[e]);
      *(u16x8*)&sA[r*32 + ((cc ^ swz4(r))*8)] = pk;
      int n = nb*64 + r;
      u16x8 bv = *(const u16x8*)(wpkih + (size_t)n*HPAD + k0*32 + cc*8);
      *(u16x8*)&sB[r*32 + ((cc ^ swz4(r))*8)] = bv;
    }
    __syncthreads();
    {
      int ar = w*16 + col;
      bf16x8 a = *(const bf16x8*)&sA[ar*32 + ((hi ^ swz4(ar))*8)];
      #pragma unroll
      for (int nt = 0; nt < 4; nt++){
        int br = nt*16 + col;
        bf16x8 b = *(const bf16x8*)&sB[br*32 + ((hi ^ swz4(br))*8)];
        acc[nt] = mfma16(a, b, acc[nt]);
      }
    }
    __syncthreads();
  }
  #pragma unroll
  for (int nt = 0; nt < 4; nt++){
    int n_g = nb*64 + nt*16 + col;
    int d = n_g / GPAD, R = n_g % GPAD;
    float bias = biasPk[n_g];
    #pragma unroll
    for (int reg = 0; reg < 4; reg++){
      int b = w*16 + hi*4 + reg;
      float val = acc[nt][reg] + bias;
      gin[(((size_t)d*SEQ + mb)*BATCH + b)*GPAD + R] = fb(val);
    }
  }
}

// ============================================================
// K2: persistent recurrent kernel (20 WGs). Protocol v3 — NO bulk
// cache ops anywhere on the step path:
//   producer: h via 8B RELAXED+AGENT atomic stores (write-through; ACKed
//             at coherence point when vmcnt drains) -> __syncthreads
//             (vmcnt(0)) -> RELAXED flag store.  [no wbl2]
//   consumer: RELAXED parallel flag poll -> __syncthreads -> h staged via
//             8B RELAXED+AGENT atomic LOADS (per-access coherent; bypass
//             stale L1/L2).                       [no buffer_inv]
// L2 keeps gin/weights warm across steps.
// ============================================================
__global__ __launch_bounds__(256,1) void k2_lstm(
    const u16* wpkhh, const u16* gin, u16* hbuf, int* flags)
{
  const int tid = threadIdx.x, lane = tid & 63, wid = tid >> 6;
  const int d = blockIdx.x / NWG_DIR, sl = blockIdx.x % NWG_DIR;
  const int mi = wid >> 1, ni = wid & 1;
  const int col = lane & 15, hi = lane >> 4;
  const int gb = tid >> 2, jq = tid & 3;     // gate phase: batch, j-octet

  __shared__ __align__(16) char smem[40960];
  u16*   sH = (u16*)smem;            // [64][320] bf16, 16B-chunk swizzled
  float* sG = (float*)smem;          // [64][133] f32 (overlays sH after MFMA)

  // resident W_hh slice fragments
  bf16x8 Bf[10][4];
  #pragma unroll
  for (int k = 0; k < 10; k++)
    #pragma unroll
    for (int nt = 0; nt < 4; nt++){
      size_t off = ((size_t)d*GPAD + sl*128 + ni*64 + nt*16 + col)*HPAD + k*32 + hi*8;
      Bf[k][nt] = *(const bf16x8*)(wpkhh + off);
    }

  float cst[8];
  #pragma unroll
  for (int q = 0; q < 8; q++) cst[q] = 0.f;

  int* myflag = flags + (d*NWG_DIR + sl)*16;

  for (int rstep = 0; rstep < SEQ; rstep++){
    int t_store = d ? (SEQ-1-rstep) : rstep;

    // ---- prefetch gin for this step (independent of h; plain cached loads)
    u16x8 gv[4];
    {
      const u16* gq = gin + (((size_t)d*SEQ + t_store)*BATCH + gb)*GPAD + sl*128 + jq*32;
      #pragma unroll
      for (int m = 0; m < 4; m++) gv[m] = *(const u16x8*)(gq + m*8);
    }

    if (rstep > 0){
      // ---- wait for all 10 producer WGs of this direction ----
      if (tid < NWG_DIR){
        const int* fp = flags + (d*NWG_DIR + tid)*16;
        while (__hip_atomic_load(fp, __ATOMIC_RELAXED, __HIP_MEMORY_SCOPE_AGENT) < rstep)
          __builtin_amdgcn_s_sleep(1);
      }
      __syncthreads();

      int t_prev = d ? (t_store+1) : (rstep-1);
      // ---- stage h(t_prev): coherent 8B atomic loads, coalesced ----
      const u64* hsrc = (const u64*)(hbuf + (size_t)(d*SEQ + t_prev)*NWG_DIR*BATCH*NH);
      #pragma unroll
      for (int q = 0; q < 20; q++){
        int f   = q*256 + tid;                 // 8B chunk id 0..5119
        int c16 = f >> 1, half = f & 1;        // 16B chunk, half
        int b   = (c16 >> 2) & 63;             // c16 = sl'*256 + b*4 + jq'
        int cch = ((c16 >> 8) << 2) + (c16 & 3);
        u64 v = __hip_atomic_load(hsrc + f, __ATOMIC_RELAXED, __HIP_MEMORY_SCOPE_AGENT);
        *(u64*)&sH[b*320 + ((cch ^ (b&7))*8) + half*4] = v;
      }
      __syncthreads();
      // ---- MFMA ----
      f32x4 acc[2][4];
      #pragma unroll
      for (int mt = 0; mt < 2; mt++)
        #pragma unroll
        for (int nt = 0; nt < 4; nt++) acc[mt][nt] = f32x4{0,0,0,0};
      #pragma unroll
      for (int k = 0; k < 10; k++){
        int c = k*4 + hi;
        int r0 = mi*32 + col, r1 = r0 + 16;
        bf16x8 a0 = *(const bf16x8*)&sH[r0*320 + ((c ^ (r0&7))*8)];
        bf16x8 a1 = *(const bf16x8*)&sH[r1*320 + ((c ^ (r1&7))*8)];
        #pragma unroll
        for (int nt = 0; nt < 4; nt++){
          acc[0][nt] = mfma16(a0, Bf[k][nt], acc[0][nt]);
          acc[1][nt] = mfma16(a1, Bf[k][nt], acc[1][nt]);
        }
      }
      __syncthreads();   // done reading sH; overlay sG
      // ---- scatter C to sG[b][133] ----
      #pragma unroll
      for (int mt = 0; mt < 2; mt++)
        #pragma unroll
        for (int nt = 0; nt < 4; nt++){
          int nl = ni*64 + nt*16 + col;
          int bb = mi*32 + mt*16 + hi*4;
          #pragma unroll
          for (int g = 0; g < 4; g++) sG[(bb+g)*133 + nl] = acc[mt][nt][g];
        }
      __syncthreads();
    }

    // ---- gates: thread owns (b=gb, j = jq*8 .. jq*8+7) ----
    u16x8 hout;
    #pragma unroll
    for (int ji = 0; ji < 8; ji++){
      float i_ = bu(gv[(ji>>1)][ (ji&1)*4 + 0 ]);
      float f_ = bu(gv[(ji>>1)][ (ji&1)*4 + 1 ]);
      float g_ = bu(gv[(ji>>1)][ (ji&1)*4 + 2 ]);
      float o_ = bu(gv[(ji>>1)][ (ji&1)*4 + 3 ]);
      if (rstep > 0){
        f32x4 r = *(const f32x4*)&sG[gb*133 + (jq*8 + ji)*4];
        i_ += r[0]; f_ += r[1]; g_ += r[2]; o_ += r[3];
      }
      float cn = sigf(f_)*cst[ji] + sigf(i_)*tanh_(g_);
      cst[ji] = cn;
      hout[ji] = (u16)fb(sigf(o_)*tanh_(cn));
    }
    // ---- write-through h store, 8B granules ----
    {
      u64* hd = (u64*)(hbuf + ((size_t)(d*SEQ + t_store)*NWG_DIR + sl)*BATCH*NH + gb*NH + jq*8);
      union { u16x8 v; u64 w[2]; } hu; hu.v = hout;
      __hip_atomic_store(hd + 0, hu.w[0], __ATOMIC_RELAXED, __HIP_MEMORY_SCOPE_AGENT);
      __hip_atomic_store(hd + 1, hu.w[1], __ATOMIC_RELAXED, __HIP_MEMORY_SCOPE_AGENT);
    }
    __syncthreads();   // vmcnt(0): stores ACKed at coherence point
    if (tid == 0)
      __hip_atomic_store(myflag, rstep + 1, __ATOMIC_RELAXED, __HIP_MEMORY_SCOPE_AGENT);
  }
}

// ============================================================
// K3: emit = [h_f | h_b] @ W_lin^T + b_lin
// ============================================================
__global__ __launch_bounds__(256) void k3_emit(
    const u16* hbuf, const float* wlin, const float* blin, float* emit)
{
  int blk = blockIdx.x;
  int t = blk >> 1, b0 = (blk & 1)*32;
  int tid = threadIdx.x;

  __shared__ u16 sh[32*600];
  __shared__ u16 swl[NTAG*600];
  __shared__ float sbl[NTAG];

  for (int p = tid; p < NTAG*600; p += 256) swl[p] = fb(wlin[p]);
  if (tid < NTAG) sbl[tid] = blin[tid];
  for (int p = tid; p < 32*600; p += 256){
    int b = p / 600, c = p % 600;
    int dd = (c < HD) ? 0 : 1;
    int c2 = (c < HD) ? c : (c - HD);
    int sl = c2 >> 5, j = c2 & 31;
    u16 v = hbuf[((size_t)(dd*SEQ + t)*NWG_DIR + sl)*BATCH*NH + (b0 + b)*NH + j];
    sh[p] = v;
  }
  __syncthreads();

  for (int p = tid; p < 32*NTAG; p += 256){
    int b = p & 31, k = p >> 5;
    const u16x8* ha = (const u16x8*)&sh[b*600];
    const u16x8* wa = (const u16x8*)&swl[k*600];
    float s = 0.f;
    #pragma unroll 5
    for (int c = 0; c < 75; c++){
      u16x8 hv = ha[c], wv = wa[c];
      #pragma unroll
      for (int e = 0; e < 8; e++) s += bu(hv[e])*bu(wv[e]);
    }
    emit[((size_t)t*BATCH + b0 + b)*NTAG + k] = s + sbl[k];
  }
}

// ============================================================
// K4: CRF forward scan + gold score + loss
// ============================================================
__global__ __launch_bounds__(256) void k4_crf(
    const float* emit, const int* tags, const float* trans, float* out)
{
  int b0 = blockIdx.x*16;
  int tid = threadIdx.x;
  __shared__ float sT[NTAG*NTAG];
  __shared__ float sd[2][16][NTAG];

  if (tid < NTAG*NTAG) sT[tid] = trans[tid];
  int b = tid / NTAG, k = tid % NTAG;
  bool act = tid < 16*NTAG;
  if (act) sd[0][b][k] = emit[((size_t)0*BATCH + b0 + b)*NTAG + k];
  __syncthreads();

  int cur = 0;
  for (int t = 1; t < SEQ; t++){
    if (act){
      float m = -1e30f;
      #pragma unroll
      for (int j = 0; j < NTAG; j++) m = fmaxf(m, sd[cur][b][j] + sT[j*NTAG + k]);
      float ssum = 0.f;
      #pragma unroll
      for (int j = 0; j < NTAG; j++) ssum += __expf(sd[cur][b][j] + sT[j*NTAG + k] - m);
      sd[cur^1][b][k] = m + __logf(ssum) + emit[((size_t)t*BATCH + b0 + b)*NTAG + k];
    }
    __syncthreads();
    cur ^= 1;
  }

  if (tid < 16){
    int bb = b0 + tid;
    const int* tg = tags + (size_t)bb*SEQ;
    float sc = 0.f; int prev = tg[0];
    sc += emit[((size_t)0*BATCH + bb)*NTAG + prev];
    for (int t = 1; t < SEQ; t++){
      int c2 = tg[t];
      sc += emit[((size_t)t*BATCH + bb)*NTAG + c2] + sT[prev*NTAG + c2];
      prev = c2;
    }
    float m = -1e30f;
    for (int k2 = 0; k2 < NTAG; k2++) m = fmaxf(m, sd[cur][tid][k2]);
    float ssum = 0.f;
    for (int k2 = 0; k2 < NTAG; k2++) ssum += __expf(sd[cur][tid][k2] - m);
    out[bb] = m + __logf(ssum) - sc;
  }
}

// ============================================================
extern "C" void kernel_launch(void* const* d_in, const int* in_sizes, int n_in,
                              void* d_out, int out_size, void* d_ws, size_t ws_size,
                              hipStream_t stream)
{
  const int*   sent  = (const int*)  d_in[0];
  const int*   tags  = (const int*)  d_in[1];
  const float* embed = (const float*)d_in[2];
  const float* wif   = (const float*)d_in[3];
  const float* whf   = (const float*)d_in[4];
  const float* bfv   = (const float*)d_in[5];
  const float* wib   = (const float*)d_in[6];
  const float* whb   = (const float*)d_in[7];
  const float* bbv   = (const float*)d_in[8];
  const float* wlin  = (const float*)d_in[9];
  const float* blin  = (const float*)d_in[10];
  const float* trans = (const float*)d_in[11];

  char* ws = (char*)d_ws;
  u16*   gin    = (u16*)  (ws + O_GIN);
  u16*   hbuf   = (u16*)  (ws + O_H);
  u16*   wpkhh  = (u16*)  (ws + O_WHH);
  u16*   wpkih  = (u16*)  (ws + O_WIH);
  float* biasPk = (float*)(ws + O_BIAS);
  float* emit   = (float*)(ws + O_EMIT);
  int*   flags  = (int*)  (ws + O_CTR);

  k0_pack<<<6400, 256, 0, stream>>>(whf, whb, wif, wib, bfv, bbv,
                                    wpkhh, wpkih, biasPk, flags);
  k1_gin<<<256*40, 256, 0, stream>>>(sent, embed, wpkih, biasPk, gin);
  k2_lstm<<<2*NWG_DIR, 256, 0, stream>>>(wpkhh, gin, hbuf, flags);
  k3_emit<<<SEQ*2, 256, 0, stream>>>(hbuf, wlin, blin, emit);
  k4_crf<<<4, 256, 0, stream>>>(emit, tags, trans, (float*)d_out);
}

// Round 7
// 1858.348 us; speedup vs baseline: 1.3952x; 1.3952x over previous
//
#include <hip/hip_runtime.h>
#include <hip/hip_bf16.h>

// ---------------- problem constants ----------------
static constexpr int BATCH = 64;
static constexpr int SEQ   = 256;
static constexpr int ED    = 300;   // embed dim
static constexpr int HD    = 300;   // hidden dim
static constexpr int HPAD  = 320;   // hidden padded to mult of 32
static constexpr int GPAD  = 1280;  // 4*HPAD, quad-interleaved gate rows
static constexpr int NTAG  = 12;
static constexpr int NWG_DIR = 10;  // recurrent WGs per direction
static constexpr int NH      = 32;  // hidden units per recurrent WG

// ---------------- workspace layout (bytes) ----------------
static constexpr size_t O_GIN  = 0;                                     // bf16 [2][SEQ][BATCH][GPAD]
static constexpr size_t SZ_GIN = (size_t)2*SEQ*BATCH*GPAD*2;            // 83,886,080
static constexpr size_t O_H    = O_GIN + SZ_GIN;                        // bf16 [2][SEQ][NWG_DIR][BATCH][32]
static constexpr size_t SZ_H   = (size_t)2*SEQ*NWG_DIR*BATCH*NH*2;      // 20,971,520
static constexpr size_t O_WHH  = O_H + SZ_H;                            // bf16 [2][GPAD][HPAD]
static constexpr size_t SZ_WHH = (size_t)2*GPAD*HPAD*2;
static constexpr size_t O_WIH  = O_WHH + SZ_WHH;                        // bf16 [2][GPAD][HPAD]
static constexpr size_t SZ_WIH = (size_t)2*GPAD*HPAD*2;
static constexpr size_t O_BIAS = O_WIH + SZ_WIH;                        // f32 [2][GPAD]
static constexpr size_t SZ_BIAS= (size_t)2*GPAD*4;
static constexpr size_t O_EMIT = O_BIAS + SZ_BIAS;                      // f32 [SEQ][BATCH][NTAG]
static constexpr size_t SZ_EMIT= (size_t)SEQ*BATCH*NTAG*4;
static constexpr size_t O_CTR  = O_EMIT + SZ_EMIT;                      // int flags[2*NWG_DIR][16]

// ---------------- types / helpers ----------------
typedef __bf16 bf16x8 __attribute__((ext_vector_type(8)));
typedef float  f32x4  __attribute__((ext_vector_type(4)));
typedef unsigned short u16x8 __attribute__((ext_vector_type(8)));
typedef unsigned short u16;

__device__ __forceinline__ float bu(u16 u){ union{unsigned i; float f;} x; x.i = ((unsigned)u)<<16; return x.f; }
__device__ __forceinline__ u16 fb(float f){ union{float f; unsigned i;} x; x.f = f; unsigned r = x.i + 0x7FFFu + ((x.i>>16)&1u); return (u16)(r>>16); }
__device__ __forceinline__ float sigf(float x){ return 1.0f/(1.0f + __expf(-x)); }
__device__ __forceinline__ float tanh_(float x){ return 2.0f*sigf(2.0f*x) - 1.0f; }
__device__ __forceinline__ f32x4 mfma16(bf16x8 a, bf16x8 b, f32x4 c){
  return __builtin_amdgcn_mfma_f32_16x16x32_bf16(a, b, c, 0, 0, 0);
}
__device__ __forceinline__ int swz4(int r){ return ((r + (r>>2)) & 3); }

// ============================================================
// K0: pack W_hh / W_ih into bf16, quad-interleaved rows (R = j*4+gate),
// zero-padded to [GPAD][HPAD]; pack bias; zero sync flags.
// ============================================================
__global__ __launch_bounds__(256) void k0_pack(
    const float* whf, const float* whb, const float* wif, const float* wib,
    const float* bfv, const float* bbv,
    u16* wpkhh, u16* wpkih, float* biasPk, int* flags)
{
  int idx = blockIdx.x*256 + threadIdx.x;                 // 0 .. 2*2*GPAD*HPAD-1
  int mat = idx / (2*GPAD*HPAD);                          // 0 = hh, 1 = ih
  int rem = idx % (2*GPAD*HPAD);
  int dd  = rem / (GPAD*HPAD);
  int rr  = rem % (GPAD*HPAD);
  int R   = rr / HPAD, kk = rr % HPAD;
  int jj  = R >> 2, gate = R & 3;
  float v = 0.f;
  if (jj < HD && kk < HD){
    const float* src = mat ? (dd ? wib : wif) : (dd ? whb : whf);
    v = src[(size_t)(gate*HD + jj)*ED + kk];              // ED == HD == 300
  }
  (mat ? wpkih : wpkhh)[rem] = fb(v);
  if (idx < 2*GPAD){
    int d2 = idx / GPAD, R2 = idx % GPAD;
    int j2 = R2 >> 2, g2 = R2 & 3;
    biasPk[idx] = (j2 < HD) ? (d2 ? bbv : bfv)[g2*HD + j2] : 0.f;
  }
  if (idx < 2*NWG_DIR*16) flags[idx] = 0;
}

// ============================================================
// K1: g_in = embed[sent] @ W_ih_packed^T + bias   (bf16 MFMA GEMM)
// ============================================================
__global__ __launch_bounds__(256) void k1_gin(
    const int* sent, const float* embed, const u16* wpkih,
    const float* biasPk, u16* gin)
{
  int blk = blockIdx.x;
  int mb = blk / 40, nb = blk % 40;     // mb == t
  int tid = threadIdx.x, lane = tid & 63, w = tid >> 6;

  __shared__ int srow[64];
  __shared__ u16 sA[64*32];
  __shared__ u16 sB[64*32];

  if (tid < 64) srow[tid] = sent[(size_t)tid*SEQ + mb];
  __syncthreads();

  f32x4 acc[4] = {f32x4{0,0,0,0},f32x4{0,0,0,0},f32x4{0,0,0,0},f32x4{0,0,0,0}};
  int r = tid >> 2, cc = tid & 3;
  int col = lane & 15, hi = lane >> 4;

  for (int k0 = 0; k0 < 10; k0++){
    {
      int kbase = k0*32 + cc*8;
      const float* erow = embed + (size_t)srow[r]*ED;
      float v[8];
      if (kbase + 8 <= ED){
        float4 p0 = *(const float4*)(erow + kbase);
        float4 p1 = *(const float4*)(erow + kbase + 4);
        v[0]=p0.x; v[1]=p0.y; v[2]=p0.z; v[3]=p0.w;
        v[4]=p1.x; v[5]=p1.y; v[6]=p1.z; v[7]=p1.w;
      } else {
        #pragma unroll
        for (int e = 0; e < 8; e++) v[e] = (kbase + e < ED) ? erow[kbase + e] : 0.f;
      }
      u16x8 pk;
      #pragma unroll
      for (int e = 0; e < 8; e++) pk[e] = fb(v[e]);
      *(u16x8*)&sA[r*32 + ((cc ^ swz4(r))*8)] = pk;
      int n = nb*64 + r;
      u16x8 bv = *(const u16x8*)(wpkih + (size_t)n*HPAD + k0*32 + cc*8);
      *(u16x8*)&sB[r*32 + ((cc ^ swz4(r))*8)] = bv;
    }
    __syncthreads();
    {
      int ar = w*16 + col;
      bf16x8 a = *(const bf16x8*)&sA[ar*32 + ((hi ^ swz4(ar))*8)];
      #pragma unroll
      for (int nt = 0; nt < 4; nt++){
        int br = nt*16 + col;
        bf16x8 b = *(const bf16x8*)&sB[br*32 + ((hi ^ swz4(br))*8)];
        acc[nt] = mfma16(a, b, acc[nt]);
      }
    }
    __syncthreads();
  }
  #pragma unroll
  for (int nt = 0; nt < 4; nt++){
    int n_g = nb*64 + nt*16 + col;
    int d = n_g / GPAD, R = n_g % GPAD;
    float bias = biasPk[n_g];
    #pragma unroll
    for (int reg = 0; reg < 4; reg++){
      int b = w*16 + hi*4 + reg;
      float val = acc[nt][reg] + bias;
      gin[(((size_t)d*SEQ + mb)*BATCH + b)*GPAD + R] = fb(val);
    }
  }
}

// ============================================================
// K2: persistent recurrent kernel (20 WGs).
//  - W_hh slice resident in LDS (80KB, loaded once; immune to the
//    per-step agent-acquire L2 invalidate)
//  - per-WG RELEASE flags (no RMW serialization); RELAXED parallel poll
//    + one agent ACQUIRE fence (R2/R4-proven protocol)
//  - gin prefetched TWO steps ahead (reg A/B buffers) so HBM/MALL
//    latency never sits on the barrier critical path
// ============================================================
__global__ __launch_bounds__(256,1) void k2_lstm(
    const u16* wpkhh, const u16* gin, u16* hbuf, int* flags)
{
  const int tid = threadIdx.x, lane = tid & 63, wid = tid >> 6;
  const int d = blockIdx.x / NWG_DIR, sl = blockIdx.x % NWG_DIR;
  const int mi = wid >> 1, ni = wid & 1;
  const int col = lane & 15, hi = lane >> 4;
  const int gb = tid >> 2, jq = tid & 3;     // gate phase: batch, j-octet

  __shared__ __align__(16) char smem[122880];
  u16*   sW = (u16*)smem;            // [128][40 chunks] bf16, chunk-swizzled
  u16*   sH = (u16*)(smem + 81920);  // [64][320] bf16, 16B-chunk swizzled
  float* sG = (float*)(smem + 81920);// [64][133] f32 (overlays sH after MFMA)

  // ---- load W_hh slice into LDS once (coalesced, swizzled) ----
  {
    const u16* wsrc = wpkhh + ((size_t)d*GPAD + sl*128)*HPAD;
    #pragma unroll
    for (int q = 0; q < 20; q++){
      int f = q*256 + tid;                 // 16B chunk 0..5119
      int r = f / 40, c = f % 40;
      u16x8 v = *(const u16x8*)(wsrc + (size_t)r*HPAD + c*8);
      *(u16x8*)&sW[(r*40 + (c ^ (r & 7)))*8] = v;
    }
  }
  __syncthreads();

  float cst[8];
  #pragma unroll
  for (int q = 0; q < 8; q++) cst[q] = 0.f;

  int* myflag = flags + (d*NWG_DIR + sl)*16;

  // ---- prefetch gin for step 0 ----
  u16x8 gvA[4], gvB[4];
  {
    int t0 = d ? (SEQ-1) : 0;
    const u16* gq = gin + (((size_t)d*SEQ + t0)*BATCH + gb)*GPAD + sl*128 + jq*32;
    #pragma unroll
    for (int m = 0; m < 4; m++) gvA[m] = *(const u16x8*)(gq + m*8);
  }

  for (int rstep = 0; rstep < SEQ; rstep++){
    int t_store = d ? (SEQ-1-rstep) : rstep;

    // ---- issue gin prefetch for NEXT step (consumed next iteration) ----
    if (rstep + 1 < SEQ){
      int t1 = d ? (SEQ-2-rstep) : (rstep+1);
      const u16* gq = gin + (((size_t)d*SEQ + t1)*BATCH + gb)*GPAD + sl*128 + jq*32;
      #pragma unroll
      for (int m = 0; m < 4; m++) gvB[m] = *(const u16x8*)(gq + m*8);
    }

    if (rstep > 0){
      // ---- wait for all 10 producer WGs of this direction ----
      if (tid < NWG_DIR){
        const int* fp = flags + (d*NWG_DIR + tid)*16;
        while (__hip_atomic_load(fp, __ATOMIC_RELAXED, __HIP_MEMORY_SCOPE_AGENT) < rstep)
          __builtin_amdgcn_s_sleep(1);
      }
      __syncthreads();
      __builtin_amdgcn_fence(__ATOMIC_ACQUIRE, "agent");

      int t_prev = d ? (t_store+1) : (rstep-1);
      // ---- stage h(t_prev): fully coalesced 16B chunks ----
      const u16* hsrc = hbuf + (size_t)(d*SEQ + t_prev)*NWG_DIR*BATCH*NH;
      #pragma unroll
      for (int q = 0; q < 10; q++){
        int f = q*256 + tid;                   // chunk id 0..2559
        int b = (f >> 2) & 63;                 // f = sl'*256 + b*4 + jq'
        int cch = ((f >> 8) << 2) + (f & 3);   // k-chunk = sl'*4 + jq'
        u16x8 v = *(const u16x8*)(hsrc + (size_t)f*8);
        *(u16x8*)&sH[b*320 + ((cch ^ (b&7))*8)] = v;
      }
      __syncthreads();
      // ---- MFMA: A from sH, B from sW ----
      f32x4 acc[2][4];
      #pragma unroll
      for (int mt = 0; mt < 2; mt++)
        #pragma unroll
        for (int nt = 0; nt < 4; nt++) acc[mt][nt] = f32x4{0,0,0,0};
      #pragma unroll
      for (int k = 0; k < 10; k++){
        int c = k*4 + hi;
        int r0 = mi*32 + col, r1 = r0 + 16;
        bf16x8 a0 = *(const bf16x8*)&sH[r0*320 + ((c ^ (r0&7))*8)];
        bf16x8 a1 = *(const bf16x8*)&sH[r1*320 + ((c ^ (r1&7))*8)];
        #pragma unroll
        for (int nt = 0; nt < 4; nt++){
          int rb = ni*64 + nt*16 + col;
          bf16x8 b = *(const bf16x8*)&sW[(rb*40 + (c ^ (rb & 7)))*8];
          acc[0][nt] = mfma16(a0, b, acc[0][nt]);
          acc[1][nt] = mfma16(a1, b, acc[1][nt]);
        }
      }
      __syncthreads();   // done reading sH; overlay sG
      // ---- scatter C to sG[b][133] ----
      #pragma unroll
      for (int mt = 0; mt < 2; mt++)
        #pragma unroll
        for (int nt = 0; nt < 4; nt++){
          int nl = ni*64 + nt*16 + col;
          int bb = mi*32 + mt*16 + hi*4;
          #pragma unroll
          for (int g = 0; g < 4; g++) sG[(bb+g)*133 + nl] = acc[mt][nt][g];
        }
      __syncthreads();
    }

    // ---- gates: thread owns (b=gb, j = jq*8 .. jq*8+7) ----
    u16x8 hout;
    #pragma unroll
    for (int ji = 0; ji < 8; ji++){
      float i_ = bu(gvA[(ji>>1)][ (ji&1)*4 + 0 ]);
      float f_ = bu(gvA[(ji>>1)][ (ji&1)*4 + 1 ]);
      float g_ = bu(gvA[(ji>>1)][ (ji&1)*4 + 2 ]);
      float o_ = bu(gvA[(ji>>1)][ (ji&1)*4 + 3 ]);
      if (rstep > 0){
        f32x4 r = *(const f32x4*)&sG[gb*133 + (jq*8 + ji)*4];
        i_ += r[0]; f_ += r[1]; g_ += r[2]; o_ += r[3];
      }
      float cn = sigf(f_)*cst[ji] + sigf(i_)*tanh_(g_);
      cst[ji] = cn;
      hout[ji] = (u16)fb(sigf(o_)*tanh_(cn));
    }
    // ---- plain 16B h store ----
    {
      u16* hdst = hbuf + ((size_t)(d*SEQ + t_store)*NWG_DIR + sl)*BATCH*NH + gb*NH + jq*8;
      *(u16x8*)hdst = hout;
    }
    __syncthreads();   // drains all threads' stores before the release
    if (tid == 0)
      __hip_atomic_store(myflag, rstep + 1, __ATOMIC_RELEASE, __HIP_MEMORY_SCOPE_AGENT);

    // ---- rotate gin prefetch buffers ----
    #pragma unroll
    for (int m = 0; m < 4; m++) gvA[m] = gvB[m];
  }
}

// ============================================================
// K3: emit = [h_f | h_b] @ W_lin^T + b_lin
// ============================================================
__global__ __launch_bounds__(256) void k3_emit(
    const u16* hbuf, const float* wlin, const float* blin, float* emit)
{
  int blk = blockIdx.x;
  int t = blk >> 1, b0 = (blk & 1)*32;
  int tid = threadIdx.x;

  __shared__ u16 sh[32*600];
  __shared__ u16 swl[NTAG*600];
  __shared__ float sbl[NTAG];

  for (int p = tid; p < NTAG*600; p += 256) swl[p] = fb(wlin[p]);
  if (tid < NTAG) sbl[tid] = blin[tid];
  for (int p = tid; p < 32*600; p += 256){
    int b = p / 600, c = p % 600;
    int dd = (c < HD) ? 0 : 1;
    int c2 = (c < HD) ? c : (c - HD);
    int sl = c2 >> 5, j = c2 & 31;
    u16 v = hbuf[((size_t)(dd*SEQ + t)*NWG_DIR + sl)*BATCH*NH + (b0 + b)*NH + j];
    sh[p] = v;
  }
  __syncthreads();

  for (int p = tid; p < 32*NTAG; p += 256){
    int b = p & 31, k = p >> 5;
    const u16x8* ha = (const u16x8*)&sh[b*600];
    const u16x8* wa = (const u16x8*)&swl[k*600];
    float s = 0.f;
    #pragma unroll 5
    for (int c = 0; c < 75; c++){
      u16x8 hv = ha[c], wv = wa[c];
      #pragma unroll
      for (int e = 0; e < 8; e++) s += bu(hv[e])*bu(wv[e]);
    }
    emit[((size_t)t*BATCH + b0 + b)*NTAG + k] = s + sbl[k];
  }
}

// ============================================================
// K4: CRF forward scan + gold score + loss
// ============================================================
__global__ __launch_bounds__(256) void k4_crf(
    const float* emit, const int* tags, const float* trans, float* out)
{
  int b0 = blockIdx.x*16;
  int tid = threadIdx.x;
  __shared__ float sT[NTAG*NTAG];
  __shared__ float sd[2][16][NTAG];

  if (tid < NTAG*NTAG) sT[tid] = trans[tid];
  int b = tid / NTAG, k = tid % NTAG;
  bool act = tid < 16*NTAG;
  if (act) sd[0][b][k] = emit[((size_t)0*BATCH + b0 + b)*NTAG + k];
  __syncthreads();

  int cur = 0;
  for (int t = 1; t < SEQ; t++){
    if (act){
      float m = -1e30f;
      #pragma unroll
      for (int j = 0; j < NTAG; j++) m = fmaxf(m, sd[cur][b][j] + sT[j*NTAG + k]);
      float ssum = 0.f;
      #pragma unroll
      for (int j = 0; j < NTAG; j++) ssum += __expf(sd[cur][b][j] + sT[j*NTAG + k] - m);
      sd[cur^1][b][k] = m + __logf(ssum) + emit[((size_t)t*BATCH + b0 + b)*NTAG + k];
    }
    __syncthreads();
    cur ^= 1;
  }

  if (tid < 16){
    int bb = b0 + tid;
    const int* tg = tags + (size_t)bb*SEQ;
    float sc = 0.f; int prev = tg[0];
    sc += emit[((size_t)0*BATCH + bb)*NTAG + prev];
    for (int t = 1; t < SEQ; t++){
      int c2 = tg[t];
      sc += emit[((size_t)t*BATCH + bb)*NTAG + c2] + sT[prev*NTAG + c2];
      prev = c2;
    }
    float m = -1e30f;
    for (int k2 = 0; k2 < NTAG; k2++) m = fmaxf(m, sd[cur][tid][k2]);
    float ssum = 0.f;
    for (int k2 = 0; k2 < NTAG; k2++) ssum += __expf(sd[cur][tid][k2] - m);
    out[bb] = m + __logf(ssum) - sc;
  }
}

// ============================================================
extern "C" void kernel_launch(void* const* d_in, const int* in_sizes, int n_in,
                              void* d_out, int out_size, void* d_ws, size_t ws_size,
                              hipStream_t stream)
{
  const int*   sent  = (const int*)  d_in[0];
  const int*   tags  = (const int*)  d_in[1];
  const float* embed = (const float*)d_in[2];
  const float* wif   = (const float*)d_in[3];
  const float* whf   = (const float*)d_in[4];
  const float* bfv   = (const float*)d_in[5];
  const float* wib   = (const float*)d_in[6];
  const float* whb   = (const float*)d_in[7];
  const float* bbv   = (const float*)d_in[8];
  const float* wlin  = (const float*)d_in[9];
  const float* blin  = (const float*)d_in[10];
  const float* trans = (const float*)d_in[11];

  char* ws = (char*)d_ws;
  u16*   gin    = (u16*)  (ws + O_GIN);
  u16*   hbuf   = (u16*)  (ws + O_H);
  u16*   wpkhh  = (u16*)  (ws + O_WHH);
  u16*   wpkih  = (u16*)  (ws + O_WIH);
  float* biasPk = (float*)(ws + O_BIAS);
  float* emit   = (float*)(ws + O_EMIT);
  int*   flags  = (int*)  (ws + O_CTR);

  k0_pack<<<6400, 256, 0, stream>>>(whf, whb, wif, wib, bfv, bbv,
                                    wpkhh, wpkih, biasPk, flags);
  k1_gin<<<256*40, 256, 0, stream>>>(sent, embed, wpkih, biasPk, gin);
  k2_lstm<<<2*NWG_DIR, 256, 0, stream>>>(wpkhh, gin, hbuf, flags);
  k3_emit<<<SEQ*2, 256, 0, stream>>>(hbuf, wlin, blin, emit);
  k4_crf<<<4, 256, 0, stream>>>(emit, tags, trans, (float*)d_out);
}